// Round 19
// baseline (423.979 us; speedup 1.0000x reference)
//
#include <hip/hip_runtime.h>
#include <math.h>

// Problem geometry (fixed by the reference):
//   preds   : (2, 2, 128, 128, 128) float32
//   targets : (2, 1, 128, 128, 128) int32
//   output  : scalar float32 = mean over (2,128,128,128) of
//             0.5*ce*(1 + 0.5*m_neg + 0.5*m_pos)
#define VOL   (128 * 128 * 128)   // 2,097,152 voxels per volume
#define NB    2                   // batch
#define TOTAL (NB * VOL)          // 4,194,304

#define INVP   0x7FFFFFFFu        // background sentinel in global parent arrays
#define FLAGB  0x80000000u        // "component has an error voxel" bit
#define IDXM   0x7FFFFFFFu        // mask off the flag bit
#define LINV   0xFFFFFFFFu        // background sentinel in LDS parent arrays

// 16x16x16 tiles: 8x8x8 tiles per volume. Faces between tiles:
// per volume 3 dirs x 7x8x8 = 1344; two volumes.
#define TPV            (8 * 8 * 8)             // tiles per volume: 512
#define FACES_PER_DIR  (7 * 8 * 8)             // 448
#define FACES_PER_VOL  (3 * FACES_PER_DIR)     // 1344
#define NFACES         (NB * FACES_PER_VOL)    // 2688

// ---------------- global union-find (atomicMin-monotone, deterministic) ----
__device__ __forceinline__ unsigned find_root(unsigned* P, unsigned i) {
    while (true) {
        unsigned p = P[i] & IDXM;
        if (p == i) return i;
        unsigned gp = P[p] & IDXM;
        if (gp != p) atomicMin(&P[i], gp);   // path-halving, never raises a ptr
        i = gp;
    }
}

__device__ __forceinline__ void unite(unsigned* P, unsigned a, unsigned b) {
    a = find_root(P, a);
    b = find_root(P, b);
    while (a != b) {
        if (b > a) { unsigned t = a; a = b; b = t; }   // link a (larger) under b
        unsigned old = atomicMin(&P[a], b);
        if (old == a) return;
        a = find_root(P, old & IDXM);
        b = find_root(P, b);
    }
}

// ---------------- LDS union-find (same invariants, tile-local ids) ---------
__device__ __forceinline__ unsigned lfind(unsigned* L, unsigned i) {
    while (true) {
        unsigned p = L[i];
        if (p == i) return i;
        unsigned gp = L[p];
        if (gp != p) atomicMin(&L[i], gp);
        i = gp;
    }
}

__device__ __forceinline__ void lunite(unsigned* L, unsigned a, unsigned b) {
    a = lfind(L, a);
    b = lfind(L, b);
    while (a != b) {
        if (b > a) { unsigned t = a; a = b; b = t; }
        unsigned old = atomicMin(&L[a], b);
        if (old == a) return;
        a = lfind(L, old);
        b = lfind(L, b);
    }
}

// Wave-dedup helper: one leader lane per distinct key among `need` lanes.
__device__ __forceinline__ bool dedup_leader(bool need, unsigned key) {
    unsigned lane = threadIdx.x & 63;
    bool leader = false;
    unsigned long long rem = __ballot(need);
    while (rem) {
        int src = __ffsll(rem) - 1;
        unsigned s = __shfl(key, src);
        if (need && key == s) {
            leader = (lane == (unsigned)src);
            need = false;
        }
        rem = __ballot(need);
    }
    return leader;
}

// ---------------- kernels ----------------

__global__ void k_zero(unsigned* __restrict__ cnts) {
    if (threadIdx.x < 4) cnts[threadIdx.x] = 0;
}

// Phase 1: fused init + tile-local CCL + tile-root list collection.
// One block = one 16x16x16 tile (4096 voxels). All intra-tile connectivity
// resolved in LDS; each voxel's global parent = global id of its tile root.
// Tile roots are appended to compact lists (LDS-aggregated, one global
// atomicAdd per block per array) so later phases can touch ROOTS ONLY
// (~tens of K) instead of walking chains from 4M voxels (R18 lesson: the
// chain walks + halving ping-pong were the cost, not the writes).
__global__ void k_local(const float* __restrict__ preds,
                        const int* __restrict__ tgt,
                        unsigned* __restrict__ Pp,
                        unsigned* __restrict__ Pt,
                        unsigned* __restrict__ listP,
                        unsigned* __restrict__ listT,
                        unsigned* __restrict__ cnts,
                        unsigned cap) {
    __shared__ unsigned lpp[4096], lpt[4096];
    __shared__ unsigned short sbuf[4096];
    __shared__ unsigned s_cnt, s_base;
    unsigned tile = blockIdx.x;                  // 0..1023
    unsigned b  = tile >> 9;                     // 512 tiles per volume
    unsigned tz = (tile >> 6) & 7, ty = (tile >> 3) & 7, tx = tile & 7;
    unsigned base_v = tz * (16 * 16384) + ty * (16 * 128) + tx * 16;
    unsigned base_g = b * VOL + base_v;

    for (int l = threadIdx.x; l < 4096; l += 256) {
        unsigned lx = l & 15, ly = (l >> 4) & 15, lz = l >> 8;
        unsigned voli = base_v + lz * 16384 + ly * 128 + lx;
        float p1 = preds[(size_t)(b * 2 + 1) * VOL + voli];   // channel-1 logit
        int   t  = tgt[b * VOL + voli];
        lpp[l] = (p1 > 0.0f) ? (unsigned)l : LINV;
        lpt[l] = (t > 0)     ? (unsigned)l : LINV;
    }
    __syncthreads();

    for (int l = threadIdx.x; l < 4096; l += 256) {
        unsigned lx = l & 15, ly = (l >> 4) & 15, lz = l >> 8;
        if (lpp[l] != LINV) {
            if (lx < 15 && lpp[l + 1]   != LINV) lunite(lpp, l, l + 1);
            if (ly < 15 && lpp[l + 16]  != LINV) lunite(lpp, l, l + 16);
            if (lz < 15 && lpp[l + 256] != LINV) lunite(lpp, l, l + 256);
        }
        if (lpt[l] != LINV) {
            if (lx < 15 && lpt[l + 1]   != LINV) lunite(lpt, l, l + 1);
            if (ly < 15 && lpt[l + 16]  != LINV) lunite(lpt, l, l + 16);
            if (lz < 15 && lpt[l + 256] != LINV) lunite(lpt, l, l + 256);
        }
    }
    __syncthreads();
    if (threadIdx.x == 0) s_cnt = 0;
    __syncthreads();

    // compress to tile root, write global parents, collect P tile roots
    for (int l = threadIdx.x; l < 4096; l += 256) {
        unsigned lx = l & 15, ly = (l >> 4) & 15, lz = l >> 8;
        unsigned g = base_g + lz * 16384 + ly * 128 + lx;
        if (lpp[l] != LINV) {
            unsigned r = lfind(lpp, l);
            Pp[g] = base_g + (r >> 8) * 16384 + ((r >> 4) & 15) * 128 + (r & 15);
            if (r == (unsigned)l) sbuf[atomicAdd(&s_cnt, 1)] = (unsigned short)l;
        } else Pp[g] = INVP;
        if (lpt[l] != LINV) {
            unsigned r = lfind(lpt, l);
            Pt[g] = base_g + (r >> 8) * 16384 + ((r >> 4) & 15) * 128 + (r & 15);
        } else Pt[g] = INVP;
    }
    __syncthreads();
    if (threadIdx.x == 0) s_base = atomicAdd(&cnts[0], s_cnt);
    __syncthreads();
    for (unsigned i = threadIdx.x; i < s_cnt; i += 256) {
        unsigned l = sbuf[i];
        if (s_base + i < cap)
            listP[s_base + i] = base_g + (l >> 8) * 16384 + ((l >> 4) & 15) * 128 + (l & 15);
    }
    __syncthreads();
    if (threadIdx.x == 0) s_cnt = 0;
    __syncthreads();
    // collect T tile roots
    for (int l = threadIdx.x; l < 4096; l += 256) {
        if (lpt[l] != LINV && lfind(lpt, l) == (unsigned)l)
            sbuf[atomicAdd(&s_cnt, 1)] = (unsigned short)l;
    }
    __syncthreads();
    if (threadIdx.x == 0) s_base = atomicAdd(&cnts[1], s_cnt);
    __syncthreads();
    for (unsigned i = threadIdx.x; i < s_cnt; i += 256) {
        unsigned l = sbuf[i];
        if (s_base + i < cap)
            listT[s_base + i] = base_g + (l >> 8) * 16384 + ((l >> 4) & 15) * 128 + (l & 15);
    }
}

// Phase 2: face-centric boundary merge (unchanged from R12 — measured cheap).
__global__ void k_bmerge(unsigned* __restrict__ Pp, unsigned* __restrict__ Pt) {
    unsigned fid = blockIdx.x;
    unsigned vol = fid / FACES_PER_VOL;
    unsigned r   = fid % FACES_PER_VOL;
    unsigned dir = r / FACES_PER_DIR;
    unsigned fr  = r % FACES_PER_DIR;
    unsigned b0 = fr % 7;
    unsigned t1 = (fr / 7) % 8;
    unsigned t2 = fr / 56;
    unsigned u = threadIdx.x & 15, v = threadIdx.x >> 4;
    unsigned lane = threadIdx.x & 63;

    unsigned x, y, z, step;
    if (dir == 0)      { x = b0 * 16 + 15; y = t1 * 16 + u; z = t2 * 16 + v; step = 1; }
    else if (dir == 1) { y = b0 * 16 + 15; x = t1 * 16 + u; z = t2 * 16 + v; step = 128; }
    else               { z = b0 * 16 + 15; x = t1 * 16 + u; y = t2 * 16 + v; step = 16384; }
    unsigned g = vol * VOL + z * 16384 + y * 128 + x;

    for (int arr = 0; arr < 2; ++arr) {
        unsigned* P = arr ? Pt : Pp;
        unsigned a = P[g];
        unsigned bb = P[g + step];
        bool need = (a != INVP) && (bb != INVP);
        bool leader = false;
        unsigned long long rem = __ballot(need);
        while (rem) {
            int src = __ffsll(rem) - 1;
            unsigned sa = __shfl(a, src), sb = __shfl(bb, src);
            if (need && a == sa && bb == sb) {
                leader = ((int)lane == src);
                need = false;
            }
            rem = __ballot(need);
        }
        if (leader) unite(P, a, bb);
    }
}

// Phase 2b: collapse every LISTED tile root directly onto its global root.
// Tiny kernel (~tens of K roots). After this, P[tile_root] == global root:
// no per-voxel kernel ever walks a chain again. Flags don't exist yet, so
// path-halving atomicMin is safe here.
__global__ void k_rcompress(unsigned* __restrict__ Pp, unsigned* __restrict__ Pt,
                            const unsigned* __restrict__ listP,
                            const unsigned* __restrict__ listT,
                            const unsigned* __restrict__ cnts, unsigned cap) {
    unsigned nP = cnts[0] < cap ? cnts[0] : cap;
    unsigned nT = cnts[1] < cap ? cnts[1] : cap;
    unsigned total = nP + nT;
    for (unsigned i = blockIdx.x * blockDim.x + threadIdx.x; i < total;
         i += gridDim.x * blockDim.x) {
        unsigned* P = (i < nP) ? Pp : Pt;
        unsigned r = (i < nP) ? listP[i] : listT[i - nP];
        unsigned rt = find_root(P, r);
        if (rt != r) atomicMin(&P[r], rt);   // direct link: tile root -> global root
    }
}

// Phase 3: per-voxel error flagging — WALK-FREE. Leader (per distinct tile
// root per wave) does one load P[tr] -> global root, then test-and-set FLAGB
// on the root entry. No halving writes, no chains (R18's 270µs was exactly
// those walks).
__global__ void k_flaga(unsigned* __restrict__ Pp, unsigned* __restrict__ Pt) {
    unsigned g = blockIdx.x * blockDim.x + threadIdx.x;
    if (g >= TOTAL) return;
    unsigned vp = Pp[g], vt = Pt[g];
    bool pf = (vp != INVP), tf = (vt != INVP);

    bool lp = dedup_leader(pf && !tf, vp & IDXM);   // m_pos: pred comp w/ err
    if (lp) {
        unsigned tr = vp & IDXM;
        unsigned root = Pp[tr] & IDXM;              // direct (rcompress'd)
        if (!(Pp[root] & FLAGB)) atomicOr(&Pp[root], FLAGB);
    }
    bool lt = dedup_leader(tf && !pf, vt & IDXM);   // m_neg: tgt comp w/ err
    if (lt) {
        unsigned tr = vt & IDXM;
        unsigned root = Pt[tr] & IDXM;
        if (!(Pt[root] & FLAGB)) atomicOr(&Pt[root], FLAGB);
    }
}

// Phase 3b: pull flags down onto the tile-root entries k_loss reads.
// Tiny kernel over the root lists (read + rare idempotent atomicOr).
__global__ void k_rpull(unsigned* __restrict__ Pp, unsigned* __restrict__ Pt,
                        const unsigned* __restrict__ listP,
                        const unsigned* __restrict__ listT,
                        const unsigned* __restrict__ cnts, unsigned cap) {
    unsigned nP = cnts[0] < cap ? cnts[0] : cap;
    unsigned nT = cnts[1] < cap ? cnts[1] : cap;
    unsigned total = nP + nT;
    for (unsigned i = blockIdx.x * blockDim.x + threadIdx.x; i < total;
         i += gridDim.x * blockDim.x) {
        unsigned* P = (i < nP) ? Pp : Pt;
        unsigned r = (i < nP) ? listP[i] : listT[i - nP];
        unsigned root = P[r] & IDXM;
        if ((P[root] & FLAGB) && !(P[r] & FLAGB)) atomicOr(&P[r], FLAGB);
    }
}

__global__ void k_loss(const float* __restrict__ preds,
                       const int* __restrict__ tgt,
                       const unsigned* __restrict__ Pp,
                       const unsigned* __restrict__ Pt,
                       float* __restrict__ partial) {
    float acc = 0.0f;
    for (unsigned g = blockIdx.x * blockDim.x + threadIdx.x; g < TOTAL;
         g += gridDim.x * blockDim.x) {
        unsigned b = g >> 21;
        unsigned i = g & (VOL - 1);
        float p0 = preds[((size_t)(b * 2 + 0)) * VOL + i];
        float p1 = preds[((size_t)(b * 2 + 1)) * VOL + i];
        int   t  = tgt[g];
        float z  = (t > 0) ? (p0 - p1) : (p1 - p0);
        float ce = (z > 0.0f) ? (z + log1pf(expf(-z))) : log1pf(expf(z));

        unsigned vp = Pp[g], vt = Pt[g];
        float crit = 0.0f;
        if (vt != INVP) {                        // direct parent = tile root
            unsigned r = vt & IDXM;
            if (Pt[r] & FLAGB) crit += 0.5f;     // BETA * m_neg
        }
        if (vp != INVP) {
            unsigned r = vp & IDXM;
            if (Pp[r] & FLAGB) crit += 0.5f;     // (1-BETA) * m_pos
        }
        acc += 0.5f * ce * (1.0f + crit);        // (1-A)*ce + A*crit*ce, A=0.5
    }
    for (int off = 32; off > 0; off >>= 1) acc += __shfl_down(acc, off);
    __shared__ float s[4];
    int wid = threadIdx.x >> 6, lane = threadIdx.x & 63;
    if (lane == 0) s[wid] = acc;
    __syncthreads();
    if (threadIdx.x == 0) {
        float tacc = 0.0f;
        for (int w = 0; w < (int)(blockDim.x >> 6); ++w) tacc += s[w];
        partial[blockIdx.x] = tacc;
    }
}

__global__ void k_final(const float* __restrict__ partial, int n,
                        float* __restrict__ out) {
    double acc = 0.0;
    for (int i = threadIdx.x; i < n; i += blockDim.x) acc += (double)partial[i];
    for (int off = 32; off > 0; off >>= 1) acc += __shfl_down(acc, off);
    __shared__ double s[4];
    int wid = threadIdx.x >> 6, lane = threadIdx.x & 63;
    if (lane == 0) s[wid] = acc;
    __syncthreads();
    if (threadIdx.x == 0) {
        double t = 0.0;
        for (int w = 0; w < (int)(blockDim.x >> 6); ++w) t += s[w];
        out[0] = (float)(t / (double)TOTAL);
    }
}

// ---------------- launch ----------------

extern "C" void kernel_launch(void* const* d_in, const int* in_sizes, int n_in,
                              void* d_out, int out_size, void* d_ws, size_t ws_size,
                              hipStream_t stream) {
    const float* preds   = (const float*)d_in[0];   // (2,2,128,128,128) f32
    const int*   targets = (const int*)d_in[1];     // (2,1,128,128,128) i32
    float*       out     = (float*)d_out;           // scalar

    // ws layout: Pp[4M] | Pt[4M] | partial[2048] f32 | cnts[4] | listP | listT
    unsigned* Pp = (unsigned*)d_ws;
    unsigned* Pt = Pp + TOTAL;
    float* partial = (float*)(Pt + TOTAL);
    unsigned* cnts = (unsigned*)(partial + 2048);
    unsigned* listP = cnts + 4;
    size_t used = (size_t)((char*)listP - (char*)d_ws);
    size_t avail = ws_size > used ? ws_size - used : 0;
    size_t cap_sz = avail / 8;                      // 2 lists x 4 bytes
    unsigned cap = cap_sz > 524288 ? 524288u : (unsigned)cap_sz;
    unsigned* listT = listP + cap;

    const int T = 256;
    const int NTILE = NB * TPV;               // 1024 16x16x16 tiles
    k_zero     <<<1, 64, 0, stream>>>(cnts);
    k_local    <<<NTILE, T, 0, stream>>>(preds, targets, Pp, Pt, listP, listT, cnts, cap);
    k_bmerge   <<<NFACES, T, 0, stream>>>(Pp, Pt);
    k_rcompress<<<128, T, 0, stream>>>(Pp, Pt, listP, listT, cnts, cap);
    k_flaga    <<<TOTAL / T, T, 0, stream>>>(Pp, Pt);
    k_rpull    <<<128, T, 0, stream>>>(Pp, Pt, listP, listT, cnts, cap);

    const int RB = 2048;
    k_loss <<<RB, T, 0, stream>>>(preds, targets, Pp, Pt, partial);
    k_final<<<1, T, 0, stream>>>(partial, RB, out);
}

// Round 20
// 287.749 us; speedup vs baseline: 1.4734x; 1.4734x over previous
//
#include <hip/hip_runtime.h>
#include <math.h>

// Problem geometry (fixed by the reference):
//   preds   : (2, 2, 128, 128, 128) float32
//   targets : (2, 1, 128, 128, 128) int32
//   output  : scalar = mean of 0.5*ce*(1 + 0.5*m_neg + 0.5*m_pos)
#define VOL   (128 * 128 * 128)
#define NB    2
#define TOTAL (NB * VOL)          // 4,194,304

#define INVP   0x7FFFFFFFu        // background sentinel in global parent arrays
#define FLAGB  0x80000000u        // "component has an error voxel" bit
#define IDXM   0x7FFFFFFFu
#define LINV   0xFFFFFFFFu        // background sentinel in LDS parent arrays

// 16x16x16 tiles: 8x8x8 per volume.
#define TPV            (8 * 8 * 8)             // 512
#define FACES_PER_DIR  (7 * 8 * 8)             // 448
#define FACES_PER_VOL  (3 * FACES_PER_DIR)     // 1344
#define NFACES         (NB * FACES_PER_VOL)    // 2688

// ---------------- global union-find (atomicMin-monotone, deterministic) ----
__device__ __forceinline__ unsigned find_root(unsigned* P, unsigned i) {
    while (true) {
        unsigned p = P[i] & IDXM;
        if (p == i) return i;
        unsigned gp = P[p] & IDXM;
        if (gp != p) atomicMin(&P[i], gp);   // halving never writes ROOT entries
        i = gp;
    }
}

__device__ __forceinline__ void unite(unsigned* P, unsigned a, unsigned b) {
    a = find_root(P, a);
    b = find_root(P, b);
    while (a != b) {
        if (b > a) { unsigned t = a; a = b; b = t; }
        unsigned old = atomicMin(&P[a], b);
        if (old == a) return;
        a = find_root(P, old & IDXM);
        b = find_root(P, b);
    }
}

// ---------------- LDS union-find ----------------
__device__ __forceinline__ unsigned lfind(unsigned* L, unsigned i) {
    while (true) {
        unsigned p = L[i];
        if (p == i) return i;
        unsigned gp = L[p];
        if (gp != p) atomicMin(&L[i], gp);
        i = gp;
    }
}

__device__ __forceinline__ void lunite(unsigned* L, unsigned a, unsigned b) {
    a = lfind(L, a);
    b = lfind(L, b);
    while (a != b) {
        if (b > a) { unsigned t = a; a = b; b = t; }
        unsigned old = atomicMin(&L[a], b);
        if (old == a) return;
        a = lfind(L, old);
        b = lfind(L, b);
    }
}

// ---------------- kernels ----------------

__global__ void k_zero(unsigned* __restrict__ cnts) {
    if (threadIdx.x < 4) cnts[threadIdx.x] = 0;
}

// Phase 1: init + tile-local CCL + per-root ERROR bit + compact root lists.
// One block = one 16x16x16 tile. Error detection is fused here (data already
// in LDS) — the list entry's top bit carries "this local component contains
// an error voxel", so NO per-voxel flag sweep is ever needed (R18 lesson:
// chain walks were the cost; R19 lesson: keep k_local's LDS <= ~34KB).
__global__ void k_local(const float* __restrict__ preds,
                        const int* __restrict__ tgt,
                        unsigned* __restrict__ Pp,
                        unsigned* __restrict__ Pt,
                        unsigned* __restrict__ listP,
                        unsigned* __restrict__ listT,
                        unsigned* __restrict__ cnts,
                        unsigned cap) {
    __shared__ unsigned lpp[4096], lpt[4096];
    __shared__ unsigned perr[128], terr[128];   // per-local-root error bitsets
    __shared__ unsigned s_scan[256];
    __shared__ unsigned s_gbase;
    unsigned tile = blockIdx.x;                  // 0..1023
    unsigned b  = tile >> 9;
    unsigned tz = (tile >> 6) & 7, ty = (tile >> 3) & 7, tx = tile & 7;
    unsigned base_v = tz * (16 * 16384) + ty * (16 * 128) + tx * 16;
    unsigned base_g = b * VOL + base_v;

    if (threadIdx.x < 128) { perr[threadIdx.x] = 0; terr[threadIdx.x] = 0; }
    for (int l = threadIdx.x; l < 4096; l += 256) {
        unsigned lx = l & 15, ly = (l >> 4) & 15, lz = l >> 8;
        unsigned voli = base_v + lz * 16384 + ly * 128 + lx;
        float p1 = preds[(size_t)(b * 2 + 1) * VOL + voli];
        int   t  = tgt[b * VOL + voli];
        lpp[l] = (p1 > 0.0f) ? (unsigned)l : LINV;
        lpt[l] = (t > 0)     ? (unsigned)l : LINV;
    }
    __syncthreads();

    for (int l = threadIdx.x; l < 4096; l += 256) {
        unsigned lx = l & 15, ly = (l >> 4) & 15, lz = l >> 8;
        if (lpp[l] != LINV) {
            if (lx < 15 && lpp[l + 1]   != LINV) lunite(lpp, l, l + 1);
            if (ly < 15 && lpp[l + 16]  != LINV) lunite(lpp, l, l + 16);
            if (lz < 15 && lpp[l + 256] != LINV) lunite(lpp, l, l + 256);
        }
        if (lpt[l] != LINV) {
            if (lx < 15 && lpt[l + 1]   != LINV) lunite(lpt, l, l + 1);
            if (ly < 15 && lpt[l + 16]  != LINV) lunite(lpt, l, l + 16);
            if (lz < 15 && lpt[l + 256] != LINV) lunite(lpt, l, l + 256);
        }
    }
    __syncthreads();

    // compress to tile root, write global parents, OR error bit onto root
    for (int l = threadIdx.x; l < 4096; l += 256) {
        unsigned lx = l & 15, ly = (l >> 4) & 15, lz = l >> 8;
        unsigned g = base_g + lz * 16384 + ly * 128 + lx;
        bool pf = lpp[l] != LINV, tf = lpt[l] != LINV;
        if (pf) {
            unsigned r = lfind(lpp, l);
            Pp[g] = base_g + (r >> 8) * 16384 + ((r >> 4) & 15) * 128 + (r & 15);
            if (!tf) atomicOr(&perr[r >> 5], 1u << (r & 31));   // m_pos err
        } else Pp[g] = INVP;
        if (tf) {
            unsigned r = lfind(lpt, l);
            Pt[g] = base_g + (r >> 8) * 16384 + ((r >> 4) & 15) * 128 + (r & 15);
            if (!pf) atomicOr(&terr[r >> 5], 1u << (r & 31));   // m_neg err
        } else Pt[g] = INVP;
    }
    __syncthreads();

    // collect roots (each thread owns l = tid + k*256), err bit in entry MSB
    for (int arr = 0; arr < 2; ++arr) {
        unsigned* L  = arr ? lpt : lpp;
        unsigned* EB = arr ? terr : perr;
        unsigned* list = arr ? listT : listP;
        unsigned myCnt = 0;
        for (int k = 0; k < 16; ++k) {
            int l = threadIdx.x + k * 256;
            if (L[l] == (unsigned)l) myCnt++;
        }
        s_scan[threadIdx.x] = myCnt;
        __syncthreads();
        for (int off = 1; off < 256; off <<= 1) {           // inclusive scan
            unsigned v = (threadIdx.x >= (unsigned)off) ? s_scan[threadIdx.x - off] : 0u;
            __syncthreads();
            s_scan[threadIdx.x] += v;
            __syncthreads();
        }
        if (threadIdx.x == 255) s_gbase = atomicAdd(&cnts[arr], s_scan[255]);
        unsigned mybase = s_scan[threadIdx.x] - myCnt;
        __syncthreads();
        unsigned w = 0;
        for (int k = 0; k < 16; ++k) {
            int l = threadIdx.x + k * 256;
            if (L[l] == (unsigned)l) {
                unsigned idx = s_gbase + mybase + (w++);
                if (idx < cap) {
                    unsigned gid = base_g + (l >> 8) * 16384 + ((l >> 4) & 15) * 128 + (l & 15);
                    unsigned eb = (EB[l >> 5] >> (l & 31)) & 1u;
                    list[idx] = gid | (eb ? FLAGB : 0u);
                }
            }
        }
        __syncthreads();
    }
}

// Phase 2: face-centric boundary merge (R12 form — measured cheap).
__global__ void k_bmerge(unsigned* __restrict__ Pp, unsigned* __restrict__ Pt) {
    unsigned fid = blockIdx.x;
    unsigned vol = fid / FACES_PER_VOL;
    unsigned r   = fid % FACES_PER_VOL;
    unsigned dir = r / FACES_PER_DIR;
    unsigned fr  = r % FACES_PER_DIR;
    unsigned b0 = fr % 7;
    unsigned t1 = (fr / 7) % 8;
    unsigned t2 = fr / 56;
    unsigned u = threadIdx.x & 15, v = threadIdx.x >> 4;
    unsigned lane = threadIdx.x & 63;

    unsigned x, y, z, step;
    if (dir == 0)      { x = b0 * 16 + 15; y = t1 * 16 + u; z = t2 * 16 + v; step = 1; }
    else if (dir == 1) { y = b0 * 16 + 15; x = t1 * 16 + u; z = t2 * 16 + v; step = 128; }
    else               { z = b0 * 16 + 15; x = t1 * 16 + u; y = t2 * 16 + v; step = 16384; }
    unsigned g = vol * VOL + z * 16384 + y * 128 + x;

    for (int arr = 0; arr < 2; ++arr) {
        unsigned* P = arr ? Pt : Pp;
        unsigned a = P[g];
        unsigned bb = P[g + step];
        bool need = (a != INVP) && (bb != INVP);
        bool leader = false;
        unsigned long long rem = __ballot(need);
        while (rem) {
            int src = __ffsll(rem) - 1;
            unsigned sa = __shfl(a, src), sb = __shfl(bb, src);
            if (need && a == sa && bb == sb) {
                leader = ((int)lane == src);
                need = false;
            }
            rem = __ballot(need);
        }
        if (leader) unite(P, a, bb);
    }
}

// Phase 2b: per listed tile root — link directly to global root AND flag the
// global root if the local component carried an error (list MSB). O(#roots).
// Safe: bmerge done => root-ness stable; halving never writes root entries;
// FLAGB lands only on global roots.
__global__ void k_rcompress(unsigned* __restrict__ Pp, unsigned* __restrict__ Pt,
                            const unsigned* __restrict__ listP,
                            const unsigned* __restrict__ listT,
                            const unsigned* __restrict__ cnts, unsigned cap) {
    unsigned nP = cnts[0] < cap ? cnts[0] : cap;
    unsigned nT = cnts[1] < cap ? cnts[1] : cap;
    unsigned total = nP + nT;
    for (unsigned i = blockIdx.x * blockDim.x + threadIdx.x; i < total;
         i += gridDim.x * blockDim.x) {
        unsigned* P = (i < nP) ? Pp : Pt;
        unsigned e = (i < nP) ? listP[i] : listT[i - nP];
        unsigned r = e & IDXM;
        unsigned rt = find_root(P, r);
        if (rt != r) atomicMin(&P[r], rt);         // direct link
        if ((e & FLAGB) && !(P[rt] & FLAGB)) atomicOr(&P[rt], FLAGB);
    }
}

// Phase 3: pull flags down onto tile-root entries (exactly what k_loss reads).
__global__ void k_rpull(unsigned* __restrict__ Pp, unsigned* __restrict__ Pt,
                        const unsigned* __restrict__ listP,
                        const unsigned* __restrict__ listT,
                        const unsigned* __restrict__ cnts, unsigned cap) {
    unsigned nP = cnts[0] < cap ? cnts[0] : cap;
    unsigned nT = cnts[1] < cap ? cnts[1] : cap;
    unsigned total = nP + nT;
    for (unsigned i = blockIdx.x * blockDim.x + threadIdx.x; i < total;
         i += gridDim.x * blockDim.x) {
        unsigned* P = (i < nP) ? Pp : Pt;
        unsigned r = ((i < nP) ? listP[i] : listT[i - nP]) & IDXM;
        unsigned root = P[r] & IDXM;               // direct after rcompress
        if ((P[root] & FLAGB) && !(P[r] & FLAGB)) atomicOr(&P[r], FLAGB);
    }
}

__global__ void k_loss(const float* __restrict__ preds,
                       const int* __restrict__ tgt,
                       const unsigned* __restrict__ Pp,
                       const unsigned* __restrict__ Pt,
                       float* __restrict__ partial) {
    float acc = 0.0f;
    for (unsigned g = blockIdx.x * blockDim.x + threadIdx.x; g < TOTAL;
         g += gridDim.x * blockDim.x) {
        unsigned b = g >> 21;
        unsigned i = g & (VOL - 1);
        float p0 = preds[((size_t)(b * 2 + 0)) * VOL + i];
        float p1 = preds[((size_t)(b * 2 + 1)) * VOL + i];
        int   t  = tgt[g];
        float z  = (t > 0) ? (p0 - p1) : (p1 - p0);
        float ce = (z > 0.0f) ? (z + log1pf(expf(-z))) : log1pf(expf(z));

        unsigned vp = Pp[g], vt = Pt[g];
        float crit = 0.0f;
        if (vt != INVP) {
            unsigned r = vt & IDXM;
            if (Pt[r] & FLAGB) crit += 0.5f;     // BETA * m_neg
        }
        if (vp != INVP) {
            unsigned r = vp & IDXM;
            if (Pp[r] & FLAGB) crit += 0.5f;     // (1-BETA) * m_pos
        }
        acc += 0.5f * ce * (1.0f + crit);
    }
    for (int off = 32; off > 0; off >>= 1) acc += __shfl_down(acc, off);
    __shared__ float s[4];
    int wid = threadIdx.x >> 6, lane = threadIdx.x & 63;
    if (lane == 0) s[wid] = acc;
    __syncthreads();
    if (threadIdx.x == 0) {
        float tacc = 0.0f;
        for (int w = 0; w < (int)(blockDim.x >> 6); ++w) tacc += s[w];
        partial[blockIdx.x] = tacc;
    }
}

__global__ void k_final(const float* __restrict__ partial, int n,
                        float* __restrict__ out) {
    double acc = 0.0;
    for (int i = threadIdx.x; i < n; i += blockDim.x) acc += (double)partial[i];
    for (int off = 32; off > 0; off >>= 1) acc += __shfl_down(acc, off);
    __shared__ double s[4];
    int wid = threadIdx.x >> 6, lane = threadIdx.x & 63;
    if (lane == 0) s[wid] = acc;
    __syncthreads();
    if (threadIdx.x == 0) {
        double t = 0.0;
        for (int w = 0; w < (int)(blockDim.x >> 6); ++w) t += s[w];
        out[0] = (float)(t / (double)TOTAL);
    }
}

// ---------------- launch ----------------

extern "C" void kernel_launch(void* const* d_in, const int* in_sizes, int n_in,
                              void* d_out, int out_size, void* d_ws, size_t ws_size,
                              hipStream_t stream) {
    const float* preds   = (const float*)d_in[0];
    const int*   targets = (const int*)d_in[1];
    float*       out     = (float*)d_out;

    // ws layout: Pp[4M] | Pt[4M] | partial[2048] f32 | cnts[4] | listP | listT
    unsigned* Pp = (unsigned*)d_ws;
    unsigned* Pt = Pp + TOTAL;
    float* partial = (float*)(Pt + TOTAL);
    unsigned* cnts = (unsigned*)(partial + 2048);
    unsigned* listP = cnts + 4;
    size_t used = (size_t)((char*)listP - (char*)d_ws);
    size_t avail = ws_size > used ? ws_size - used : 0;
    size_t cap_sz = avail / 8;
    unsigned cap = cap_sz > 524288 ? 524288u : (unsigned)cap_sz;
    unsigned* listT = listP + cap;

    const int T = 256;
    const int NTILE = NB * TPV;               // 1024 tiles
    k_zero     <<<1, 64, 0, stream>>>(cnts);
    k_local    <<<NTILE, T, 0, stream>>>(preds, targets, Pp, Pt, listP, listT, cnts, cap);
    k_bmerge   <<<NFACES, T, 0, stream>>>(Pp, Pt);
    k_rcompress<<<128, T, 0, stream>>>(Pp, Pt, listP, listT, cnts, cap);
    k_rpull    <<<128, T, 0, stream>>>(Pp, Pt, listP, listT, cnts, cap);

    const int RB = 2048;
    k_loss <<<RB, T, 0, stream>>>(preds, targets, Pp, Pt, partial);
    k_final<<<1, T, 0, stream>>>(partial, RB, out);
}

// Round 21
// 261.624 us; speedup vs baseline: 1.6206x; 1.0999x over previous
//
#include <hip/hip_runtime.h>
#include <math.h>

// Problem geometry (fixed by the reference):
//   preds   : (2, 2, 128, 128, 128) float32
//   targets : (2, 1, 128, 128, 128) int32
//   output  : scalar = mean of 0.5*ce*(1 + 0.5*m_neg + 0.5*m_pos)
#define VOL   (128 * 128 * 128)
#define NB    2
#define TOTAL (NB * VOL)          // 4,194,304

#define INVP   0x7FFFFFFFu        // background sentinel in global parent arrays
#define FLAGB  0x80000000u        // "component has an error voxel" bit
#define TAGB   0x40000000u        // list-entry tag: 0 = pred array, 1 = tgt
#define GIDM   0x3FFFFFFFu        // list-entry gid mask (gid < 4M fits)
#define IDXM   0x7FFFFFFFu
#define LINV   0xFFFFFFFFu        // background sentinel in LDS parent arrays

// 16x16x16 tiles: 8x8x8 per volume.
#define TPV            (8 * 8 * 8)             // 512
#define FACES_PER_DIR  (7 * 8 * 8)             // 448
#define FACES_PER_VOL  (3 * FACES_PER_DIR)     // 1344
#define NFACES         (NB * FACES_PER_VOL)    // 2688

// ---------------- global union-find (atomicMin-monotone, deterministic) ----
__device__ __forceinline__ unsigned find_root(unsigned* P, unsigned i) {
    while (true) {
        unsigned p = P[i] & IDXM;
        if (p == i) return i;
        unsigned gp = P[p] & IDXM;
        if (gp != p) atomicMin(&P[i], gp);   // halving never writes ROOT entries
        i = gp;
    }
}

__device__ __forceinline__ void unite(unsigned* P, unsigned a, unsigned b) {
    a = find_root(P, a);
    b = find_root(P, b);
    while (a != b) {
        if (b > a) { unsigned t = a; a = b; b = t; }
        unsigned old = atomicMin(&P[a], b);
        if (old == a) return;
        a = find_root(P, old & IDXM);
        b = find_root(P, b);
    }
}

// ---------------- LDS union-find ----------------
__device__ __forceinline__ unsigned lfind(unsigned* L, unsigned i) {
    while (true) {
        unsigned p = L[i];
        if (p == i) return i;
        unsigned gp = L[p];
        if (gp != p) atomicMin(&L[i], gp);
        i = gp;
    }
}

__device__ __forceinline__ void lunite(unsigned* L, unsigned a, unsigned b) {
    a = lfind(L, a);
    b = lfind(L, b);
    while (a != b) {
        if (b > a) { unsigned t = a; a = b; b = t; }
        unsigned old = atomicMin(&L[a], b);
        if (old == a) return;
        a = lfind(L, old);
        b = lfind(L, b);
    }
}

// ---------------- kernels ----------------

__global__ void k_zero(unsigned* __restrict__ cnts) {
    if (threadIdx.x < 4) cnts[threadIdx.x] = 0;
}

// Phase 1: init + tile-local CCL + per-root ERROR bit + ONE combined root
// list (tag bit selects array, MSB carries error). One block = one 16^3 tile.
// Vectorized init (float4/int4 + ds_write_b128) since this kernel is
// VALU-bound (R20: 32% VALUBusy, 6% HBM).
__global__ void k_local(const float* __restrict__ preds,
                        const int* __restrict__ tgt,
                        unsigned* __restrict__ Pp,
                        unsigned* __restrict__ Pt,
                        unsigned* __restrict__ list,
                        unsigned* __restrict__ cnts,
                        unsigned cap) {
    __shared__ unsigned lpp[4096], lpt[4096];
    __shared__ unsigned perr[128], terr[128];   // per-local-root error bitsets
    __shared__ unsigned s_scan[256];
    __shared__ unsigned s_gbase;
    unsigned tile = blockIdx.x;                  // 0..1023
    unsigned b  = tile >> 9;
    unsigned tz = (tile >> 6) & 7, ty = (tile >> 3) & 7, tx = tile & 7;
    unsigned base_v = tz * (16 * 16384) + ty * (16 * 128) + tx * 16;
    unsigned base_g = b * VOL + base_v;

    if (threadIdx.x < 128) { perr[threadIdx.x] = 0; terr[threadIdx.x] = 0; }
    // vectorized init: 4 consecutive x-voxels per thread per iteration
    for (int base = threadIdx.x * 4; base < 4096; base += 1024) {
        unsigned lx = base & 15, ly = (base >> 4) & 15, lz = base >> 8;
        unsigned voli = base_v + lz * 16384 + ly * 128 + lx;
        float4 p1 = *reinterpret_cast<const float4*>(
            preds + (size_t)(b * 2 + 1) * VOL + voli);
        int4  t4 = *reinterpret_cast<const int4*>(tgt + b * VOL + voli);
        uint4 vp, vt;
        vp.x = (p1.x > 0.0f) ? (unsigned)(base + 0) : LINV;
        vp.y = (p1.y > 0.0f) ? (unsigned)(base + 1) : LINV;
        vp.z = (p1.z > 0.0f) ? (unsigned)(base + 2) : LINV;
        vp.w = (p1.w > 0.0f) ? (unsigned)(base + 3) : LINV;
        vt.x = (t4.x > 0) ? (unsigned)(base + 0) : LINV;
        vt.y = (t4.y > 0) ? (unsigned)(base + 1) : LINV;
        vt.z = (t4.z > 0) ? (unsigned)(base + 2) : LINV;
        vt.w = (t4.w > 0) ? (unsigned)(base + 3) : LINV;
        *reinterpret_cast<uint4*>(&lpp[base]) = vp;
        *reinterpret_cast<uint4*>(&lpt[base]) = vt;
    }
    __syncthreads();

    for (int l = threadIdx.x; l < 4096; l += 256) {
        unsigned lx = l & 15, ly = (l >> 4) & 15, lz = l >> 8;
        if (lpp[l] != LINV) {
            if (lx < 15 && lpp[l + 1]   != LINV) lunite(lpp, l, l + 1);
            if (ly < 15 && lpp[l + 16]  != LINV) lunite(lpp, l, l + 16);
            if (lz < 15 && lpp[l + 256] != LINV) lunite(lpp, l, l + 256);
        }
        if (lpt[l] != LINV) {
            if (lx < 15 && lpt[l + 1]   != LINV) lunite(lpt, l, l + 1);
            if (ly < 15 && lpt[l + 16]  != LINV) lunite(lpt, l, l + 16);
            if (lz < 15 && lpt[l + 256] != LINV) lunite(lpt, l, l + 256);
        }
    }
    __syncthreads();

    // compress to tile root, write global parents, OR error bit onto root
    for (int l = threadIdx.x; l < 4096; l += 256) {
        unsigned lx = l & 15, ly = (l >> 4) & 15, lz = l >> 8;
        unsigned g = base_g + lz * 16384 + ly * 128 + lx;
        bool pf = lpp[l] != LINV, tf = lpt[l] != LINV;
        if (pf) {
            unsigned r = lfind(lpp, l);
            Pp[g] = base_g + (r >> 8) * 16384 + ((r >> 4) & 15) * 128 + (r & 15);
            if (!tf) atomicOr(&perr[r >> 5], 1u << (r & 31));   // m_pos err
        } else Pp[g] = INVP;
        if (tf) {
            unsigned r = lfind(lpt, l);
            Pt[g] = base_g + (r >> 8) * 16384 + ((r >> 4) & 15) * 128 + (r & 15);
            if (!pf) atomicOr(&terr[r >> 5], 1u << (r & 31));   // m_neg err
        } else Pt[g] = INVP;
    }
    __syncthreads();

    // collect roots of BOTH arrays into one list with a single scan.
    // Each thread owns l = tid + k*256.
    unsigned myCnt = 0;
    for (int k = 0; k < 16; ++k) {
        int l = threadIdx.x + k * 256;
        myCnt += (lpp[l] == (unsigned)l) + (lpt[l] == (unsigned)l);
    }
    s_scan[threadIdx.x] = myCnt;
    __syncthreads();
    for (int off = 1; off < 256; off <<= 1) {           // inclusive scan
        unsigned v = (threadIdx.x >= (unsigned)off) ? s_scan[threadIdx.x - off] : 0u;
        __syncthreads();
        s_scan[threadIdx.x] += v;
        __syncthreads();
    }
    if (threadIdx.x == 255) s_gbase = atomicAdd(&cnts[0], s_scan[255]);
    unsigned mybase = s_scan[threadIdx.x] - myCnt;
    __syncthreads();
    unsigned idx = s_gbase + mybase;
    for (int k = 0; k < 16; ++k) {
        int l = threadIdx.x + k * 256;
        unsigned gid = base_g + (l >> 8) * 16384 + ((l >> 4) & 15) * 128 + (l & 15);
        if (lpp[l] == (unsigned)l) {
            if (idx < cap) {
                unsigned eb = (perr[l >> 5] >> (l & 31)) & 1u;
                list[idx] = gid | (eb ? FLAGB : 0u);
            }
            idx++;
        }
        if (lpt[l] == (unsigned)l) {
            if (idx < cap) {
                unsigned eb = (terr[l >> 5] >> (l & 31)) & 1u;
                list[idx] = gid | TAGB | (eb ? FLAGB : 0u);
            }
            idx++;
        }
    }
}

// Phase 2: face-centric boundary merge (R12 form — measured cheap).
__global__ void k_bmerge(unsigned* __restrict__ Pp, unsigned* __restrict__ Pt) {
    unsigned fid = blockIdx.x;
    unsigned vol = fid / FACES_PER_VOL;
    unsigned r   = fid % FACES_PER_VOL;
    unsigned dir = r / FACES_PER_DIR;
    unsigned fr  = r % FACES_PER_DIR;
    unsigned b0 = fr % 7;
    unsigned t1 = (fr / 7) % 8;
    unsigned t2 = fr / 56;
    unsigned u = threadIdx.x & 15, v = threadIdx.x >> 4;
    unsigned lane = threadIdx.x & 63;

    unsigned x, y, z, step;
    if (dir == 0)      { x = b0 * 16 + 15; y = t1 * 16 + u; z = t2 * 16 + v; step = 1; }
    else if (dir == 1) { y = b0 * 16 + 15; x = t1 * 16 + u; z = t2 * 16 + v; step = 128; }
    else               { z = b0 * 16 + 15; x = t1 * 16 + u; y = t2 * 16 + v; step = 16384; }
    unsigned g = vol * VOL + z * 16384 + y * 128 + x;

    for (int arr = 0; arr < 2; ++arr) {
        unsigned* P = arr ? Pt : Pp;
        unsigned a = P[g];
        unsigned bb = P[g + step];
        bool need = (a != INVP) && (bb != INVP);
        bool leader = false;
        unsigned long long rem = __ballot(need);
        while (rem) {
            int src = __ffsll(rem) - 1;
            unsigned sa = __shfl(a, src), sb = __shfl(bb, src);
            if (need && a == sa && bb == sb) {
                leader = ((int)lane == src);
                need = false;
            }
            rem = __ballot(need);
        }
        if (leader) unite(P, a, bb);
    }
}

// Phase 2b: per listed tile root — link directly to global root AND flag the
// global root if the local component carried an error (entry MSB). O(#roots).
// Safe: bmerge done => root-ness fixed; halving writes only non-roots; FLAGB
// lands only on global roots; direct-link targets are non-roots.
__global__ void k_rcompress(unsigned* __restrict__ Pp, unsigned* __restrict__ Pt,
                            const unsigned* __restrict__ list,
                            const unsigned* __restrict__ cnts, unsigned cap) {
    unsigned n = cnts[0] < cap ? cnts[0] : cap;
    for (unsigned i = blockIdx.x * blockDim.x + threadIdx.x; i < n;
         i += gridDim.x * blockDim.x) {
        unsigned e = list[i];
        unsigned* P = (e & TAGB) ? Pt : Pp;
        unsigned r = e & GIDM;
        unsigned rt = find_root(P, r);
        if (rt != r) atomicMin(&P[r], rt);         // direct link
        if ((e & FLAGB) && !(P[rt] & FLAGB)) atomicOr(&P[rt], FLAGB);
    }
}

// Phase 3: pull flags down onto tile-root entries (exactly what k_loss reads).
__global__ void k_rpull(unsigned* __restrict__ Pp, unsigned* __restrict__ Pt,
                        const unsigned* __restrict__ list,
                        const unsigned* __restrict__ cnts, unsigned cap) {
    unsigned n = cnts[0] < cap ? cnts[0] : cap;
    for (unsigned i = blockIdx.x * blockDim.x + threadIdx.x; i < n;
         i += gridDim.x * blockDim.x) {
        unsigned e = list[i];
        unsigned* P = (e & TAGB) ? Pt : Pp;
        unsigned r = e & GIDM;
        unsigned root = P[r] & IDXM;               // direct after rcompress
        if ((P[root] & FLAGB) && !(P[r] & FLAGB)) atomicOr(&P[r], FLAGB);
    }
}

__global__ void k_loss(const float* __restrict__ preds,
                       const int* __restrict__ tgt,
                       const unsigned* __restrict__ Pp,
                       const unsigned* __restrict__ Pt,
                       float* __restrict__ partial) {
    float acc = 0.0f;
    for (unsigned g4 = (blockIdx.x * blockDim.x + threadIdx.x) * 4; g4 < TOTAL;
         g4 += gridDim.x * blockDim.x * 4) {
        unsigned b = g4 >> 21;
        unsigned i = g4 & (VOL - 1);
        float4 p0 = *reinterpret_cast<const float4*>(preds + (size_t)(b * 2 + 0) * VOL + i);
        float4 p1 = *reinterpret_cast<const float4*>(preds + (size_t)(b * 2 + 1) * VOL + i);
        int4  t4  = *reinterpret_cast<const int4*>(tgt + g4);
        uint4 vp4 = *reinterpret_cast<const uint4*>(Pp + g4);
        uint4 vt4 = *reinterpret_cast<const uint4*>(Pt + g4);
        float p0a[4] = {p0.x, p0.y, p0.z, p0.w};
        float p1a[4] = {p1.x, p1.y, p1.z, p1.w};
        int   ta[4]  = {t4.x, t4.y, t4.z, t4.w};
        unsigned vpa[4] = {vp4.x, vp4.y, vp4.z, vp4.w};
        unsigned vta[4] = {vt4.x, vt4.y, vt4.z, vt4.w};
        #pragma unroll
        for (int j = 0; j < 4; ++j) {
            float z  = (ta[j] > 0) ? (p0a[j] - p1a[j]) : (p1a[j] - p0a[j]);
            float ce = (z > 0.0f) ? (z + log1pf(expf(-z))) : log1pf(expf(z));
            float crit = 0.0f;
            if (vta[j] != INVP) {
                unsigned r = vta[j] & IDXM;
                if (Pt[r] & FLAGB) crit += 0.5f;     // BETA * m_neg
            }
            if (vpa[j] != INVP) {
                unsigned r = vpa[j] & IDXM;
                if (Pp[r] & FLAGB) crit += 0.5f;     // (1-BETA) * m_pos
            }
            acc += 0.5f * ce * (1.0f + crit);
        }
    }
    for (int off = 32; off > 0; off >>= 1) acc += __shfl_down(acc, off);
    __shared__ float s[4];
    int wid = threadIdx.x >> 6, lane = threadIdx.x & 63;
    if (lane == 0) s[wid] = acc;
    __syncthreads();
    if (threadIdx.x == 0) {
        float tacc = 0.0f;
        for (int w = 0; w < (int)(blockDim.x >> 6); ++w) tacc += s[w];
        partial[blockIdx.x] = tacc;
    }
}

__global__ void k_final(const float* __restrict__ partial, int n,
                        float* __restrict__ out) {
    double acc = 0.0;
    for (int i = threadIdx.x; i < n; i += blockDim.x) acc += (double)partial[i];
    for (int off = 32; off > 0; off >>= 1) acc += __shfl_down(acc, off);
    __shared__ double s[4];
    int wid = threadIdx.x >> 6, lane = threadIdx.x & 63;
    if (lane == 0) s[wid] = acc;
    __syncthreads();
    if (threadIdx.x == 0) {
        double t = 0.0;
        for (int w = 0; w < (int)(blockDim.x >> 6); ++w) t += s[w];
        out[0] = (float)(t / (double)TOTAL);
    }
}

// ---------------- launch ----------------

extern "C" void kernel_launch(void* const* d_in, const int* in_sizes, int n_in,
                              void* d_out, int out_size, void* d_ws, size_t ws_size,
                              hipStream_t stream) {
    const float* preds   = (const float*)d_in[0];
    const int*   targets = (const int*)d_in[1];
    float*       out     = (float*)d_out;

    // ws layout: Pp[4M] | Pt[4M] | partial[2048] f32 | cnts[4] | list
    unsigned* Pp = (unsigned*)d_ws;
    unsigned* Pt = Pp + TOTAL;
    float* partial = (float*)(Pt + TOTAL);
    unsigned* cnts = (unsigned*)(partial + 2048);
    unsigned* list = cnts + 4;
    size_t used = (size_t)((char*)list - (char*)d_ws);
    size_t avail = ws_size > used ? ws_size - used : 0;
    size_t cap_sz = avail / 4;
    unsigned cap = cap_sz > 1048576 ? 1048576u : (unsigned)cap_sz;

    const int T = 256;
    const int NTILE = NB * TPV;               // 1024 tiles
    k_zero     <<<1, 64, 0, stream>>>(cnts);
    k_local    <<<NTILE, T, 0, stream>>>(preds, targets, Pp, Pt, list, cnts, cap);
    k_bmerge   <<<NFACES, T, 0, stream>>>(Pp, Pt);
    k_rcompress<<<128, T, 0, stream>>>(Pp, Pt, list, cnts, cap);
    k_rpull    <<<128, T, 0, stream>>>(Pp, Pt, list, cnts, cap);

    const int RB = 2048;
    k_loss <<<RB, T, 0, stream>>>(preds, targets, Pp, Pt, partial);
    k_final<<<1, T, 0, stream>>>(partial, RB, out);
}